// Round 4
// baseline (420.598 us; speedup 1.0000x reference)
//
#include <hip/hip_runtime.h>
#include <hip/hip_bf16.h>

#define N_NODES 50000
#define N_EDGES 800000
#define IN_F 256
#define OUT_F 32
#define NHEAD 8
#define HD 256      // NHEAD*OUT_F
#define EDGE_F 32
#define N_ETYPES 8
#define NEG_SLOPE 0.1f
#define CAP 64      // per-node LDS s-cache depth (avg deg=16)
#define ALDS 264    // padded LDS row stride in shorts (264*2=528B, 33*16B)

typedef __attribute__((ext_vector_type(8))) short short8;
typedef __attribute__((ext_vector_type(4))) short short4_t;
typedef __attribute__((ext_vector_type(4))) float f32x4;

__device__ __forceinline__ short f2b(float f) {
    __hip_bfloat16 t = __float2bfloat16(f);
    return __builtin_bit_cast(short, t);
}
__device__ __forceinline__ float b2f(short s) {
    return __uint_as_float(((unsigned)(unsigned short)s) << 16);
}

// ---- prep: Wt cast (blocks 0..255), Wlr build (block 256), he (block 257) ----
__global__ void prep(const float* __restrict__ W,
                     const float* __restrict__ a_l,
                     const float* __restrict__ a_r,
                     const float* __restrict__ edge_emb,
                     const float* __restrict__ W_e,
                     const float* __restrict__ a_e,
                     __hip_bfloat16* __restrict__ Wt,
                     __hip_bfloat16* __restrict__ Wlr,
                     float* __restrict__ he) {
    int b = blockIdx.x, tid = threadIdx.x;
    if (b < 256) {
        // Wt[n][k] = bf16(W[k][n]); n = b, k = tid
        Wt[b * 256 + tid] = __float2bfloat16(W[tid * 256 + b]);
    } else if (b == 256) {
        // Wlr[j][k]: j<8 -> a_l head j; j>=8 -> a_r head j-8. thread owns k=tid.
        int k = tid;
        #pragma unroll
        for (int j = 0; j < 16; ++j) {
            const float* av = (j < 8) ? a_l : a_r;
            int hh = j & 7;
            float acc = 0.f;
            #pragma unroll
            for (int d = 0; d < 32; ++d)
                acc += W[k * 256 + hh * 32 + d] * av[hh * 32 + d];
            Wlr[j * 256 + k] = __float2bfloat16(acc);
        }
    } else {
        if (tid < N_ETYPES * NHEAD) {
            int t = tid >> 3, hh = tid & 7;
            float acc = 0.f;
            for (int f = 0; f < EDGE_F; ++f) {
                float ev = 0.f;
                for (int k = 0; k < EDGE_F; ++k)
                    ev += edge_emb[t * EDGE_F + k] * W_e[k * (EDGE_F * NHEAD) + hh * EDGE_F + f];
                acc += a_e[hh * EDGE_F + f] * ev;
            }
            he[t * NHEAD + hh] = acc;
        }
    }
}

// ---- h(bf16) = bf16(x) @ Wt^T via MFMA, LDS-staged A, fused hl/hr columns ----
// block = 256 thr (4 waves), BM=64 rows, BN=256; wave w owns cols [w*64, w*64+64)
// wave 0 additionally computes 16 "logit columns" (8 hl + 8 hr) via Wlr.
__global__ __launch_bounds__(256) void gemm_h_mfma(const float* __restrict__ x,
                                                   const __hip_bfloat16* __restrict__ Wt,
                                                   const __hip_bfloat16* __restrict__ Wlr,
                                                   __hip_bfloat16* __restrict__ h,
                                                   float* __restrict__ hl,
                                                   float* __restrict__ hr) {
    __shared__ short As[64 * ALDS];   // bf16 x-tile, padded rows
    const int tid = threadIdx.x;
    const int wave = tid >> 6;
    const int lane = tid & 63;
    const int row0 = blockIdx.x * 64;
    const int wn0  = wave * 64;
    const int l15  = lane & 15;
    const int kg   = lane >> 4;

    // stage A: thread converts 64 contiguous k of one row (64 cvts, once per block)
    {
        int arow = tid >> 2;                 // 0..63
        int kbase = (tid & 3) * 64;          // 0,64,128,192
        int grow = row0 + arow;
        const float* xp = &x[(size_t)(grow < N_NODES ? grow : N_NODES - 1) * IN_F + kbase];
        #pragma unroll
        for (int i = 0; i < 8; ++i) {
            float4 lo = *(const float4*)(xp + i * 8);
            float4 hi = *(const float4*)(xp + i * 8 + 4);
            short8 v;
            v[0] = f2b(lo.x); v[1] = f2b(lo.y); v[2] = f2b(lo.z); v[3] = f2b(lo.w);
            v[4] = f2b(hi.x); v[5] = f2b(hi.y); v[6] = f2b(hi.z); v[7] = f2b(hi.w);
            *(short8*)&As[arow * ALDS + kbase + i * 8] = v;
        }
    }
    __syncthreads();

    f32x4 acc[4][4];
    f32x4 accLR[4];
    #pragma unroll
    for (int mi = 0; mi < 4; ++mi) {
        accLR[mi] = (f32x4){0.f, 0.f, 0.f, 0.f};
        #pragma unroll
        for (int ni = 0; ni < 4; ++ni)
            acc[mi][ni] = (f32x4){0.f, 0.f, 0.f, 0.f};
    }

    for (int k0 = 0; k0 < IN_F; k0 += 32) {
        short8 afrag[4];
        #pragma unroll
        for (int mi = 0; mi < 4; ++mi)
            afrag[mi] = *(const short8*)&As[(mi * 16 + l15) * ALDS + k0 + kg * 8];
        short8 bfrag[4];
        #pragma unroll
        for (int ni = 0; ni < 4; ++ni)
            bfrag[ni] = *(const short8*)&Wt[(size_t)(wn0 + ni * 16 + l15) * 256 + k0 + kg * 8];
        #pragma unroll
        for (int mi = 0; mi < 4; ++mi)
            #pragma unroll
            for (int ni = 0; ni < 4; ++ni)
                acc[mi][ni] = __builtin_amdgcn_mfma_f32_16x16x32_bf16(
                    afrag[mi], bfrag[ni], acc[mi][ni], 0, 0, 0);
        if (wave == 0) {
            short8 blr = *(const short8*)&Wlr[(size_t)l15 * 256 + k0 + kg * 8];
            #pragma unroll
            for (int mi = 0; mi < 4; ++mi)
                accLR[mi] = __builtin_amdgcn_mfma_f32_16x16x32_bf16(
                    afrag[mi], blr, accLR[mi], 0, 0, 0);
        }
    }

    // C/D layout: col = lane&15, row = (lane>>4)*4 + reg   [m89-verified]
    #pragma unroll
    for (int mi = 0; mi < 4; ++mi) {
        #pragma unroll
        for (int r = 0; r < 4; ++r) {
            int grow = row0 + mi * 16 + kg * 4 + r;
            if (grow < N_NODES) {
                #pragma unroll
                for (int ni = 0; ni < 4; ++ni) {
                    float v = acc[mi][ni][r];
                    v = (v != v) ? 0.f : v;   // NaN guard per reference
                    h[(size_t)grow * HD + wn0 + ni * 16 + l15] = __float2bfloat16(v);
                }
            }
        }
    }
    if (wave == 0) {
        #pragma unroll
        for (int mi = 0; mi < 4; ++mi) {
            #pragma unroll
            for (int r = 0; r < 4; ++r) {
                int grow = row0 + mi * 16 + kg * 4 + r;
                if (grow < N_NODES) {
                    float v = accLR[mi][r];
                    if (l15 < 8) hl[grow * 8 + l15] = v;
                    else         hr[grow * 8 + (l15 - 8)] = v;
                }
            }
        }
    }
}

// ---- CSR build (pos saved; scatter writes packed payload) ----
__global__ void calc_deg(const int* __restrict__ col, int* __restrict__ deg,
                         int* __restrict__ pos) {
    int e = blockIdx.x * 256 + threadIdx.x;
    if (e < N_EDGES) pos[e] = atomicAdd(&deg[col[e]], 1);
}

__global__ void scan1(const int* __restrict__ deg, int* __restrict__ excl,
                      int* __restrict__ bsums, int n) {
    __shared__ int sm[256];
    int tid = threadIdx.x;
    int i = blockIdx.x * 256 + tid;
    int v = (i < n) ? deg[i] : 0;
    sm[tid] = v;
    __syncthreads();
    int acc = v;
    for (int off = 1; off < 256; off <<= 1) {
        int add = (tid >= off) ? sm[tid - off] : 0;
        __syncthreads();
        acc += add;
        sm[tid] = acc;
        __syncthreads();
    }
    if (i < n) excl[i] = acc - v;
    if (tid == 255) bsums[blockIdx.x] = acc;
}

__global__ void scan2(int* __restrict__ bsums, int nb) {
    __shared__ int sm[256];
    int tid = threadIdx.x;
    int v = (tid < nb) ? bsums[tid] : 0;
    sm[tid] = v;
    __syncthreads();
    int acc = v;
    for (int off = 1; off < 256; off <<= 1) {
        int add = (tid >= off) ? sm[tid - off] : 0;
        __syncthreads();
        acc += add;
        sm[tid] = acc;
        __syncthreads();
    }
    if (tid < nb) bsums[tid] = acc - v;   // exclusive
}

__global__ void scan3(int* __restrict__ offs, const int* __restrict__ bsums,
                      int n, int total) {
    int i = blockIdx.x * 256 + threadIdx.x;
    if (i < n) offs[i] += bsums[blockIdx.x];
    if (i == 0) offs[n] = total;
}

__global__ void scatter_edges(const int* __restrict__ col,
                              const int* __restrict__ row,
                              const int* __restrict__ tp,
                              const int* __restrict__ offs,
                              const int* __restrict__ pos,
                              int2* __restrict__ epack) {
    int e = blockIdx.x * 256 + threadIdx.x;
    if (e < N_EDGES) {
        int c = col[e];
        epack[offs[c] + pos[e]] = make_int2(row[e] | (tp[e] << 17), e);
    }
}

// ---- fused per-node softmax + aggregation: one wave/node, online m,z ----
__global__ __launch_bounds__(256) void node_fused(const int* __restrict__ offs,
                                                  const int2* __restrict__ epack,
                                                  const float* __restrict__ hl,
                                                  const float* __restrict__ hr,
                                                  const float* __restrict__ he,
                                                  const __hip_bfloat16* __restrict__ h,
                                                  float* __restrict__ out,
                                                  float* __restrict__ att) {
    __shared__ float sc[4][CAP][8];
    int wid = threadIdx.x >> 6;
    int lane = threadIdx.x & 63;
    int n = blockIdx.x * 4 + wid;
    if (n >= N_NODES) return;
    int beg = offs[n], end = offs[n + 1], deg = end - beg;

    // pass A: online (m,z); lanes = 8 slots x 8 heads; cache s in LDS
    int slot = lane >> 3, hh = lane & 7;
    float hrv = hr[n * 8 + hh];
    float m = -1e30f, z = 0.f;
    for (int jj = slot; jj < deg; jj += 8) {
        int2 p = epack[beg + jj];
        int r = p.x & 0x1FFFF, t = p.x >> 17;
        float s = hl[r * 8 + hh] + hrv + he[t * 8 + hh];
        s = s > 0.f ? s : NEG_SLOPE * s;
        if (jj < CAP) sc[wid][jj][hh] = s;
        if (s > m) { z = z * __expf(m - s) + 1.f; m = s; }
        else       { z += __expf(s - m); }
    }
    {
        float mo, zo, M;
        mo = __shfl_xor(m, 8);  zo = __shfl_xor(z, 8);
        M = fmaxf(m, mo); z = z * __expf(m - M) + zo * __expf(mo - M); m = M;
        mo = __shfl_xor(m, 16); zo = __shfl_xor(z, 16);
        M = fmaxf(m, mo); z = z * __expf(m - M) + zo * __expf(mo - M); m = M;
        mo = __shfl_xor(m, 32); zo = __shfl_xor(z, 32);
        M = fmaxf(m, mo); z = z * __expf(m - M) + zo * __expf(mo - M); m = M;
    }
    float zinv = 1.0f / z;

    // pass B: lane = head(lane>>3) x 4-col group; gather bf16 h rows (2x unroll)
    int hh3 = lane >> 3, dg = lane & 7;
    float m3 = __shfl(m, hh3);
    float zinv3 = __shfl(zinv, hh3);
    float hrv3 = __shfl(hrv, hh3);

    float4 acc = make_float4(0.f, 0.f, 0.f, 0.f);
    int jj = 0;
    for (; jj + 2 <= deg; jj += 2) {
        int2 p0 = epack[beg + jj];
        int2 p1 = epack[beg + jj + 1];
        int r0 = p0.x & 0x1FFFF, r1 = p1.x & 0x1FFFF;
        short4_t hv0 = *(const short4_t*)&h[(size_t)r0 * HD + lane * 4];
        short4_t hv1 = *(const short4_t*)&h[(size_t)r1 * HD + lane * 4];
        float s0, s1;
        if (jj < CAP)     s0 = sc[wid][jj][hh3];
        else { int t = p0.x >> 17; s0 = hl[r0 * 8 + hh3] + hrv3 + he[t * 8 + hh3];
               s0 = s0 > 0.f ? s0 : NEG_SLOPE * s0; }
        if (jj + 1 < CAP) s1 = sc[wid][jj + 1][hh3];
        else { int t = p1.x >> 17; s1 = hl[r1 * 8 + hh3] + hrv3 + he[t * 8 + hh3];
               s1 = s1 > 0.f ? s1 : NEG_SLOPE * s1; }
        float a0 = __expf(s0 - m3) * zinv3;
        float a1 = __expf(s1 - m3) * zinv3;
        if (dg == 0) {
            att[(size_t)p0.y * 8 + hh3] = a0;
            att[(size_t)p1.y * 8 + hh3] = a1;
        }
        acc.x += a0 * b2f(hv0[0]) + a1 * b2f(hv1[0]);
        acc.y += a0 * b2f(hv0[1]) + a1 * b2f(hv1[1]);
        acc.z += a0 * b2f(hv0[2]) + a1 * b2f(hv1[2]);
        acc.w += a0 * b2f(hv0[3]) + a1 * b2f(hv1[3]);
    }
    for (; jj < deg; ++jj) {
        int2 p = epack[beg + jj];
        int r = p.x & 0x1FFFF;
        float s;
        if (jj < CAP) s = sc[wid][jj][hh3];
        else { int t = p.x >> 17; s = hl[r * 8 + hh3] + hrv3 + he[t * 8 + hh3];
               s = s > 0.f ? s : NEG_SLOPE * s; }
        float a = __expf(s - m3) * zinv3;
        if (dg == 0) att[(size_t)p.y * 8 + hh3] = a;
        short4_t hv = *(const short4_t*)&h[(size_t)r * HD + lane * 4];
        acc.x += a * b2f(hv[0]);
        acc.y += a * b2f(hv[1]);
        acc.z += a * b2f(hv[2]);
        acc.w += a * b2f(hv[3]);
    }
    *(float4*)&out[(size_t)n * HD + lane * 4] = acc;
}

extern "C" void kernel_launch(void* const* d_in, const int* in_sizes, int n_in,
                              void* d_out, int out_size, void* d_ws, size_t ws_size,
                              hipStream_t stream) {
    const float* x        = (const float*)d_in[0];
    const float* W        = (const float*)d_in[1];
    const float* W_e      = (const float*)d_in[2];
    const float* edge_emb = (const float*)d_in[3];
    const float* a_l      = (const float*)d_in[4];
    const float* a_r      = (const float*)d_in[5];
    const float* a_e      = (const float*)d_in[6];
    const int*   row      = (const int*)d_in[7];
    const int*   col      = (const int*)d_in[8];
    const int*   tp       = (const int*)d_in[9];

    float* out = (float*)d_out;                       // [N, 256] f32
    float* att = out + (size_t)N_NODES * HD;          // [E, 8]   f32

    // workspace layout (4-byte words)
    __hip_bfloat16* h   = (__hip_bfloat16*)d_ws;      // 12,800,000 bf16 -> 6,400,000 w
    float* hl           = (float*)(h + 12800000);     //    400,000
    float* hr           = hl + 400000;                //    400,000
    float* he           = hr + 400000;                //         64
    __hip_bfloat16* Wt  = (__hip_bfloat16*)(he + 64); //  65,536 bf16 -> 32,768 w
    __hip_bfloat16* Wlr = Wt + 65536;                 //   4,096 bf16 ->  2,048 w
    int*   deg          = (int*)(Wlr + 4096);         //     50,000  [zeroed]
    int*   offs         = deg + 50000;                //     50,001
    int*   bsums        = offs + 50001;               //        256
    int*   pos          = bsums + 256;                //    800,000
    int*   pad          = pos + 800000;               //          1 (align epack to 8B)
    int2*  epack        = (int2*)((((uintptr_t)pad) + 7) & ~(uintptr_t)7);  // 800,000 int2

    hipMemsetAsync(deg, 0, (size_t)50000 * 4, stream);

    prep<<<258, 256, 0, stream>>>(W, a_l, a_r, edge_emb, W_e, a_e, Wt, Wlr, he);

    gemm_h_mfma<<<(N_NODES + 63) / 64, 256, 0, stream>>>(x, Wt, Wlr, h, hl, hr);

    const int EB = (N_EDGES + 255) / 256;   // 3125
    calc_deg<<<EB, 256, 0, stream>>>(col, deg, pos);

    const int NB = (N_NODES + 255) / 256;   // 196
    scan1<<<NB, 256, 0, stream>>>(deg, offs, bsums, N_NODES);
    scan2<<<1, 256, 0, stream>>>(bsums, NB);
    scan3<<<NB, 256, 0, stream>>>(offs, bsums, N_NODES, N_EDGES);
    scatter_edges<<<EB, 256, 0, stream>>>(col, row, tp, offs, pos, epack);

    node_fused<<<(N_NODES + 3) / 4, 256, 0, stream>>>(offs, epack, hl, hr, he, h, out, att);
}

// Round 5
// 326.106 us; speedup vs baseline: 1.2898x; 1.2898x over previous
//
#include <hip/hip_runtime.h>
#include <hip/hip_bf16.h>

#define N_NODES 50000
#define N_EDGES 800000
#define IN_F 256
#define OUT_F 32
#define NHEAD 8
#define HD 256      // NHEAD*OUT_F
#define EDGE_F 32
#define N_ETYPES 8
#define NEG_SLOPE 0.1f
#define CAP 64      // per-node LDS s-cache depth (avg deg=16)
#define ALDS 264    // padded LDS row stride in shorts (264*2=528B, 33*16B)

typedef __attribute__((ext_vector_type(8))) short short8;
typedef __attribute__((ext_vector_type(4))) short short4_t;
typedef __attribute__((ext_vector_type(4))) float f32x4;

__device__ __forceinline__ short f2b(float f) {
    __hip_bfloat16 t = __float2bfloat16(f);
    return __builtin_bit_cast(short, t);
}
__device__ __forceinline__ float b2f(short s) {
    return __uint_as_float(((unsigned)(unsigned short)s) << 16);
}

// ---- prep: Wt cast (blocks 0..255), Wlr build (blocks 256..271), he (block 272) ----
__global__ void prep(const float* __restrict__ W,
                     const float* __restrict__ a_l,
                     const float* __restrict__ a_r,
                     const float* __restrict__ edge_emb,
                     const float* __restrict__ W_e,
                     const float* __restrict__ a_e,
                     __hip_bfloat16* __restrict__ Wt,
                     __hip_bfloat16* __restrict__ Wlr,
                     float* __restrict__ he) {
    int b = blockIdx.x, tid = threadIdx.x;
    if (b < 256) {
        // Wt[n][k] = bf16(W[k][n]); n = b, k = tid
        Wt[b * 256 + tid] = __float2bfloat16(W[tid * 256 + b]);
    } else if (b < 272) {
        // Wlr[j][k], one thread per (k,j); 16 lanes share a k (broadcast reads)
        int idx = (b - 256) * 256 + tid;      // 0..4095
        int k = idx >> 4, j = idx & 15;
        const float* av = (j < 8) ? a_l : a_r;
        int hh = j & 7;
        float acc = 0.f;
        #pragma unroll
        for (int d = 0; d < 32; ++d)
            acc += W[k * 256 + hh * 32 + d] * av[hh * 32 + d];
        Wlr[j * 256 + k] = __float2bfloat16(acc);
    } else {
        if (tid < N_ETYPES * NHEAD) {
            int t = tid >> 3, hh = tid & 7;
            float acc = 0.f;
            for (int f = 0; f < EDGE_F; ++f) {
                float ev = 0.f;
                for (int k = 0; k < EDGE_F; ++k)
                    ev += edge_emb[t * EDGE_F + k] * W_e[k * (EDGE_F * NHEAD) + hh * EDGE_F + f];
                acc += a_e[hh * EDGE_F + f] * ev;
            }
            he[t * NHEAD + hh] = acc;
        }
    }
}

// ---- h(bf16) = bf16(x) @ Wt^T via MFMA, LDS-staged A, fused hl/hr columns ----
// block = 256 thr (4 waves), BM=64 rows, BN=256; wave w owns cols [w*64, w*64+64)
// wave 0 additionally computes 16 "logit columns" (8 hl + 8 hr) via Wlr.
__global__ __launch_bounds__(256) void gemm_h_mfma(const float* __restrict__ x,
                                                   const __hip_bfloat16* __restrict__ Wt,
                                                   const __hip_bfloat16* __restrict__ Wlr,
                                                   __hip_bfloat16* __restrict__ h,
                                                   float* __restrict__ hl,
                                                   float* __restrict__ hr) {
    __shared__ short As[64 * ALDS];   // bf16 x-tile, padded rows
    const int tid = threadIdx.x;
    const int wave = tid >> 6;
    const int lane = tid & 63;
    const int row0 = blockIdx.x * 64;
    const int wn0  = wave * 64;
    const int l15  = lane & 15;
    const int kg   = lane >> 4;

    // stage A: thread converts 64 contiguous k of one row (64 cvts, once per block)
    {
        int arow = tid >> 2;                 // 0..63
        int kbase = (tid & 3) * 64;          // 0,64,128,192
        int grow = row0 + arow;
        const float* xp = &x[(size_t)(grow < N_NODES ? grow : N_NODES - 1) * IN_F + kbase];
        #pragma unroll
        for (int i = 0; i < 8; ++i) {
            float4 lo = *(const float4*)(xp + i * 8);
            float4 hi = *(const float4*)(xp + i * 8 + 4);
            short8 v;
            v[0] = f2b(lo.x); v[1] = f2b(lo.y); v[2] = f2b(lo.z); v[3] = f2b(lo.w);
            v[4] = f2b(hi.x); v[5] = f2b(hi.y); v[6] = f2b(hi.z); v[7] = f2b(hi.w);
            *(short8*)&As[arow * ALDS + kbase + i * 8] = v;
        }
    }
    __syncthreads();

    f32x4 acc[4][4];
    f32x4 accLR[4];
    #pragma unroll
    for (int mi = 0; mi < 4; ++mi) {
        accLR[mi] = (f32x4){0.f, 0.f, 0.f, 0.f};
        #pragma unroll
        for (int ni = 0; ni < 4; ++ni)
            acc[mi][ni] = (f32x4){0.f, 0.f, 0.f, 0.f};
    }

    for (int k0 = 0; k0 < IN_F; k0 += 32) {
        short8 afrag[4];
        #pragma unroll
        for (int mi = 0; mi < 4; ++mi)
            afrag[mi] = *(const short8*)&As[(mi * 16 + l15) * ALDS + k0 + kg * 8];
        short8 bfrag[4];
        #pragma unroll
        for (int ni = 0; ni < 4; ++ni)
            bfrag[ni] = *(const short8*)&Wt[(size_t)(wn0 + ni * 16 + l15) * 256 + k0 + kg * 8];
        #pragma unroll
        for (int mi = 0; mi < 4; ++mi)
            #pragma unroll
            for (int ni = 0; ni < 4; ++ni)
                acc[mi][ni] = __builtin_amdgcn_mfma_f32_16x16x32_bf16(
                    afrag[mi], bfrag[ni], acc[mi][ni], 0, 0, 0);
        if (wave == 0) {
            short8 blr = *(const short8*)&Wlr[(size_t)l15 * 256 + k0 + kg * 8];
            #pragma unroll
            for (int mi = 0; mi < 4; ++mi)
                accLR[mi] = __builtin_amdgcn_mfma_f32_16x16x32_bf16(
                    afrag[mi], blr, accLR[mi], 0, 0, 0);
        }
    }

    // C/D layout: col = lane&15, row = (lane>>4)*4 + reg   [m89-verified]
    #pragma unroll
    for (int mi = 0; mi < 4; ++mi) {
        #pragma unroll
        for (int r = 0; r < 4; ++r) {
            int grow = row0 + mi * 16 + kg * 4 + r;
            if (grow < N_NODES) {
                #pragma unroll
                for (int ni = 0; ni < 4; ++ni) {
                    float v = acc[mi][ni][r];
                    v = (v != v) ? 0.f : v;   // NaN guard per reference
                    h[(size_t)grow * HD + wn0 + ni * 16 + l15] = __float2bfloat16(v);
                }
            }
        }
    }
    if (wave == 0) {
        #pragma unroll
        for (int mi = 0; mi < 4; ++mi) {
            #pragma unroll
            for (int r = 0; r < 4; ++r) {
                int grow = row0 + mi * 16 + kg * 4 + r;
                if (grow < N_NODES) {
                    float v = accLR[mi][r];
                    if (l15 < 8) hl[grow * 8 + l15] = v;
                    else         hr[grow * 8 + (l15 - 8)] = v;
                }
            }
        }
    }
}

// ---- CSR build (pos saved; scatter writes packed payload) ----
__global__ void calc_deg(const int* __restrict__ col, int* __restrict__ deg,
                         int* __restrict__ pos) {
    int e = blockIdx.x * 256 + threadIdx.x;
    if (e < N_EDGES) pos[e] = atomicAdd(&deg[col[e]], 1);
}

__global__ void scan1(const int* __restrict__ deg, int* __restrict__ excl,
                      int* __restrict__ bsums, int n) {
    __shared__ int sm[256];
    int tid = threadIdx.x;
    int i = blockIdx.x * 256 + tid;
    int v = (i < n) ? deg[i] : 0;
    sm[tid] = v;
    __syncthreads();
    int acc = v;
    for (int off = 1; off < 256; off <<= 1) {
        int add = (tid >= off) ? sm[tid - off] : 0;
        __syncthreads();
        acc += add;
        sm[tid] = acc;
        __syncthreads();
    }
    if (i < n) excl[i] = acc - v;
    if (tid == 255) bsums[blockIdx.x] = acc;
}

__global__ void scan2(int* __restrict__ bsums, int nb) {
    __shared__ int sm[256];
    int tid = threadIdx.x;
    int v = (tid < nb) ? bsums[tid] : 0;
    sm[tid] = v;
    __syncthreads();
    int acc = v;
    for (int off = 1; off < 256; off <<= 1) {
        int add = (tid >= off) ? sm[tid - off] : 0;
        __syncthreads();
        acc += add;
        sm[tid] = acc;
        __syncthreads();
    }
    if (tid < nb) bsums[tid] = acc - v;   // exclusive
}

__global__ void scan3(int* __restrict__ offs, const int* __restrict__ bsums,
                      int n, int total) {
    int i = blockIdx.x * 256 + threadIdx.x;
    if (i < n) offs[i] += bsums[blockIdx.x];
    if (i == 0) offs[n] = total;
}

__global__ void scatter_edges(const int* __restrict__ col,
                              const int* __restrict__ row,
                              const int* __restrict__ tp,
                              const int* __restrict__ offs,
                              const int* __restrict__ pos,
                              int2* __restrict__ epack) {
    int e = blockIdx.x * 256 + threadIdx.x;
    if (e < N_EDGES) {
        int c = col[e];
        epack[offs[c] + pos[e]] = make_int2(row[e] | (tp[e] << 17), e);
    }
}

// ---- fused per-node softmax + aggregation: one wave/node, online m,z ----
__global__ __launch_bounds__(256) void node_fused(const int* __restrict__ offs,
                                                  const int2* __restrict__ epack,
                                                  const float* __restrict__ hl,
                                                  const float* __restrict__ hr,
                                                  const float* __restrict__ he,
                                                  const __hip_bfloat16* __restrict__ h,
                                                  float* __restrict__ out,
                                                  float* __restrict__ att) {
    __shared__ float sc[4][CAP][8];
    int wid = threadIdx.x >> 6;
    int lane = threadIdx.x & 63;
    int n = blockIdx.x * 4 + wid;
    if (n >= N_NODES) return;
    int beg = offs[n], end = offs[n + 1], deg = end - beg;

    // pass A: online (m,z); lanes = 8 slots x 8 heads; cache s in LDS
    int slot = lane >> 3, hh = lane & 7;
    float hrv = hr[n * 8 + hh];
    float m = -1e30f, z = 0.f;
    for (int jj = slot; jj < deg; jj += 8) {
        int2 p = epack[beg + jj];
        int r = p.x & 0x1FFFF, t = p.x >> 17;
        float s = hl[r * 8 + hh] + hrv + he[t * 8 + hh];
        s = s > 0.f ? s : NEG_SLOPE * s;
        if (jj < CAP) sc[wid][jj][hh] = s;
        if (s > m) { z = z * __expf(m - s) + 1.f; m = s; }
        else       { z += __expf(s - m); }
    }
    {
        float mo, zo, M;
        mo = __shfl_xor(m, 8);  zo = __shfl_xor(z, 8);
        M = fmaxf(m, mo); z = z * __expf(m - M) + zo * __expf(mo - M); m = M;
        mo = __shfl_xor(m, 16); zo = __shfl_xor(z, 16);
        M = fmaxf(m, mo); z = z * __expf(m - M) + zo * __expf(mo - M); m = M;
        mo = __shfl_xor(m, 32); zo = __shfl_xor(z, 32);
        M = fmaxf(m, mo); z = z * __expf(m - M) + zo * __expf(mo - M); m = M;
    }
    float zinv = 1.0f / z;

    // pass B: lane = head(lane>>3) x 4-col group; gather bf16 h rows (2x unroll)
    int hh3 = lane >> 3, dg = lane & 7;
    float m3 = __shfl(m, hh3);
    float zinv3 = __shfl(zinv, hh3);
    float hrv3 = __shfl(hrv, hh3);

    float4 acc = make_float4(0.f, 0.f, 0.f, 0.f);
    int jj = 0;
    for (; jj + 2 <= deg; jj += 2) {
        int2 p0 = epack[beg + jj];
        int2 p1 = epack[beg + jj + 1];
        int r0 = p0.x & 0x1FFFF, r1 = p1.x & 0x1FFFF;
        short4_t hv0 = *(const short4_t*)&h[(size_t)r0 * HD + lane * 4];
        short4_t hv1 = *(const short4_t*)&h[(size_t)r1 * HD + lane * 4];
        float s0, s1;
        if (jj < CAP)     s0 = sc[wid][jj][hh3];
        else { int t = p0.x >> 17; s0 = hl[r0 * 8 + hh3] + hrv3 + he[t * 8 + hh3];
               s0 = s0 > 0.f ? s0 : NEG_SLOPE * s0; }
        if (jj + 1 < CAP) s1 = sc[wid][jj + 1][hh3];
        else { int t = p1.x >> 17; s1 = hl[r1 * 8 + hh3] + hrv3 + he[t * 8 + hh3];
               s1 = s1 > 0.f ? s1 : NEG_SLOPE * s1; }
        float a0 = __expf(s0 - m3) * zinv3;
        float a1 = __expf(s1 - m3) * zinv3;
        if (dg == 0) {
            att[(size_t)p0.y * 8 + hh3] = a0;
            att[(size_t)p1.y * 8 + hh3] = a1;
        }
        acc.x += a0 * b2f(hv0[0]) + a1 * b2f(hv1[0]);
        acc.y += a0 * b2f(hv0[1]) + a1 * b2f(hv1[1]);
        acc.z += a0 * b2f(hv0[2]) + a1 * b2f(hv1[2]);
        acc.w += a0 * b2f(hv0[3]) + a1 * b2f(hv1[3]);
    }
    for (; jj < deg; ++jj) {
        int2 p = epack[beg + jj];
        int r = p.x & 0x1FFFF;
        float s;
        if (jj < CAP) s = sc[wid][jj][hh3];
        else { int t = p.x >> 17; s = hl[r * 8 + hh3] + hrv3 + he[t * 8 + hh3];
               s = s > 0.f ? s : NEG_SLOPE * s; }
        float a = __expf(s - m3) * zinv3;
        if (dg == 0) att[(size_t)p.y * 8 + hh3] = a;
        short4_t hv = *(const short4_t*)&h[(size_t)r * HD + lane * 4];
        acc.x += a * b2f(hv[0]);
        acc.y += a * b2f(hv[1]);
        acc.z += a * b2f(hv[2]);
        acc.w += a * b2f(hv[3]);
    }
    *(float4*)&out[(size_t)n * HD + lane * 4] = acc;
}

extern "C" void kernel_launch(void* const* d_in, const int* in_sizes, int n_in,
                              void* d_out, int out_size, void* d_ws, size_t ws_size,
                              hipStream_t stream) {
    const float* x        = (const float*)d_in[0];
    const float* W        = (const float*)d_in[1];
    const float* W_e      = (const float*)d_in[2];
    const float* edge_emb = (const float*)d_in[3];
    const float* a_l      = (const float*)d_in[4];
    const float* a_r      = (const float*)d_in[5];
    const float* a_e      = (const float*)d_in[6];
    const int*   row      = (const int*)d_in[7];
    const int*   col      = (const int*)d_in[8];
    const int*   tp       = (const int*)d_in[9];

    float* out = (float*)d_out;                       // [N, 256] f32
    float* att = out + (size_t)N_NODES * HD;          // [E, 8]   f32

    // workspace layout (4-byte words)
    __hip_bfloat16* h   = (__hip_bfloat16*)d_ws;      // 12,800,000 bf16 -> 6,400,000 w
    float* hl           = (float*)(h + 12800000);     //    400,000
    float* hr           = hl + 400000;                //    400,000
    float* he           = hr + 400000;                //         64
    __hip_bfloat16* Wt  = (__hip_bfloat16*)(he + 64); //  65,536 bf16 -> 32,768 w
    __hip_bfloat16* Wlr = Wt + 65536;                 //   4,096 bf16 ->  2,048 w
    int*   deg          = (int*)(Wlr + 4096);         //     50,000  [zeroed]
    int*   offs         = deg + 50000;                //     50,001
    int*   bsums        = offs + 50001;               //        256
    int*   pos          = bsums + 256;                //    800,000
    int*   pad          = pos + 800000;               //          1 (align epack to 8B)
    int2*  epack        = (int2*)((((uintptr_t)pad) + 7) & ~(uintptr_t)7);  // 800,000 int2

    hipMemsetAsync(deg, 0, (size_t)50000 * 4, stream);

    prep<<<273, 256, 0, stream>>>(W, a_l, a_r, edge_emb, W_e, a_e, Wt, Wlr, he);

    gemm_h_mfma<<<(N_NODES + 63) / 64, 256, 0, stream>>>(x, Wt, Wlr, h, hl, hr);

    const int EB = (N_EDGES + 255) / 256;   // 3125
    calc_deg<<<EB, 256, 0, stream>>>(col, deg, pos);

    const int NB = (N_NODES + 255) / 256;   // 196
    scan1<<<NB, 256, 0, stream>>>(deg, offs, bsums, N_NODES);
    scan2<<<1, 256, 0, stream>>>(bsums, NB);
    scan3<<<NB, 256, 0, stream>>>(offs, bsums, N_NODES, N_EDGES);
    scatter_edges<<<EB, 256, 0, stream>>>(col, row, tp, offs, pos, epack);

    node_fused<<<(N_NODES + 3) / 4, 256, 0, stream>>>(offs, epack, hl, hr, he, h, out, att);
}

// Round 6
// 298.731 us; speedup vs baseline: 1.4079x; 1.0916x over previous
//
#include <hip/hip_runtime.h>
#include <hip/hip_bf16.h>

#define N_NODES 50000
#define N_EDGES 800000
#define IN_F 256
#define OUT_F 32
#define NHEAD 8
#define HD 256      // NHEAD*OUT_F
#define EDGE_F 32
#define N_ETYPES 8
#define NEG_SLOPE 0.1f
#define CAP 64      // per-node LDS cache depth (avg deg=16)
#define ALDS 264    // padded LDS row stride in shorts (264*2=528B)

typedef __attribute__((ext_vector_type(8))) short short8;
typedef __attribute__((ext_vector_type(4))) short short4_t;
typedef __attribute__((ext_vector_type(4))) float f32x4;

__device__ __forceinline__ short f2b(float f) {
    __hip_bfloat16 t = __float2bfloat16(f);
    return __builtin_bit_cast(short, t);
}
__device__ __forceinline__ float b2f(short s) {
    return __uint_as_float(((unsigned)(unsigned short)s) << 16);
}

// ---- prep: Wt cast (0..255), Wlr (256..271), he (272), calc_deg (273..) ----
__global__ void prep(const float* __restrict__ W,
                     const float* __restrict__ a_l,
                     const float* __restrict__ a_r,
                     const float* __restrict__ edge_emb,
                     const float* __restrict__ W_e,
                     const float* __restrict__ a_e,
                     const int* __restrict__ col,
                     __hip_bfloat16* __restrict__ Wt,
                     __hip_bfloat16* __restrict__ Wlr,
                     float* __restrict__ he,
                     int* __restrict__ deg,
                     int* __restrict__ pos) {
    int b = blockIdx.x, tid = threadIdx.x;
    if (b < 256) {
        // Wt[n][k] = bf16(W[k][n]); n = b, k = tid
        Wt[b * 256 + tid] = __float2bfloat16(W[tid * 256 + b]);
    } else if (b < 272) {
        // Wlr[j][k], one thread per (k,j); 16 lanes share a k (broadcast reads)
        int idx = (b - 256) * 256 + tid;      // 0..4095
        int k = idx >> 4, j = idx & 15;
        const float* av = (j < 8) ? a_l : a_r;
        int hh = j & 7;
        float acc = 0.f;
        #pragma unroll
        for (int d = 0; d < 32; ++d)
            acc += W[k * 256 + hh * 32 + d] * av[hh * 32 + d];
        Wlr[j * 256 + k] = __float2bfloat16(acc);
    } else if (b == 272) {
        if (tid < N_ETYPES * NHEAD) {
            int t = tid >> 3, hh = tid & 7;
            float acc = 0.f;
            for (int f = 0; f < EDGE_F; ++f) {
                float ev = 0.f;
                for (int k = 0; k < EDGE_F; ++k)
                    ev += edge_emb[t * EDGE_F + k] * W_e[k * (EDGE_F * NHEAD) + hh * EDGE_F + f];
                acc += a_e[hh * EDGE_F + f] * ev;
            }
            he[t * NHEAD + hh] = acc;
        }
    } else {
        int e = (b - 273) * 256 + tid;
        if (e < N_EDGES) pos[e] = atomicAdd(&deg[col[e]], 1);
    }
}

// ---- h(bf16) = bf16(x) @ Wt^T via MFMA, LDS-staged A, fused hl/hr columns ----
__global__ __launch_bounds__(256) void gemm_h_mfma(const float* __restrict__ x,
                                                   const __hip_bfloat16* __restrict__ Wt,
                                                   const __hip_bfloat16* __restrict__ Wlr,
                                                   __hip_bfloat16* __restrict__ h,
                                                   float* __restrict__ hl,
                                                   float* __restrict__ hr) {
    __shared__ short As[64 * ALDS];   // bf16 x-tile, padded rows
    const int tid = threadIdx.x;
    const int wave = tid >> 6;
    const int lane = tid & 63;
    const int row0 = blockIdx.x * 64;
    const int wn0  = wave * 64;
    const int l15  = lane & 15;
    const int kg   = lane >> 4;

    {
        int arow = tid >> 2;                 // 0..63
        int kbase = (tid & 3) * 64;          // 0,64,128,192
        int grow = row0 + arow;
        const float* xp = &x[(size_t)(grow < N_NODES ? grow : N_NODES - 1) * IN_F + kbase];
        #pragma unroll
        for (int i = 0; i < 8; ++i) {
            float4 lo = *(const float4*)(xp + i * 8);
            float4 hi = *(const float4*)(xp + i * 8 + 4);
            short8 v;
            v[0] = f2b(lo.x); v[1] = f2b(lo.y); v[2] = f2b(lo.z); v[3] = f2b(lo.w);
            v[4] = f2b(hi.x); v[5] = f2b(hi.y); v[6] = f2b(hi.z); v[7] = f2b(hi.w);
            *(short8*)&As[arow * ALDS + kbase + i * 8] = v;
        }
    }
    __syncthreads();

    f32x4 acc[4][4];
    f32x4 accLR[4];
    #pragma unroll
    for (int mi = 0; mi < 4; ++mi) {
        accLR[mi] = (f32x4){0.f, 0.f, 0.f, 0.f};
        #pragma unroll
        for (int ni = 0; ni < 4; ++ni)
            acc[mi][ni] = (f32x4){0.f, 0.f, 0.f, 0.f};
    }

    for (int k0 = 0; k0 < IN_F; k0 += 32) {
        short8 afrag[4];
        #pragma unroll
        for (int mi = 0; mi < 4; ++mi)
            afrag[mi] = *(const short8*)&As[(mi * 16 + l15) * ALDS + k0 + kg * 8];
        short8 bfrag[4];
        #pragma unroll
        for (int ni = 0; ni < 4; ++ni)
            bfrag[ni] = *(const short8*)&Wt[(size_t)(wn0 + ni * 16 + l15) * 256 + k0 + kg * 8];
        #pragma unroll
        for (int mi = 0; mi < 4; ++mi)
            #pragma unroll
            for (int ni = 0; ni < 4; ++ni)
                acc[mi][ni] = __builtin_amdgcn_mfma_f32_16x16x32_bf16(
                    afrag[mi], bfrag[ni], acc[mi][ni], 0, 0, 0);
        if (wave == 0) {
            short8 blr = *(const short8*)&Wlr[(size_t)l15 * 256 + k0 + kg * 8];
            #pragma unroll
            for (int mi = 0; mi < 4; ++mi)
                accLR[mi] = __builtin_amdgcn_mfma_f32_16x16x32_bf16(
                    afrag[mi], blr, accLR[mi], 0, 0, 0);
        }
    }

    // C/D layout: col = lane&15, row = (lane>>4)*4 + reg   [m89-verified]
    #pragma unroll
    for (int mi = 0; mi < 4; ++mi) {
        #pragma unroll
        for (int r = 0; r < 4; ++r) {
            int grow = row0 + mi * 16 + kg * 4 + r;
            if (grow < N_NODES) {
                #pragma unroll
                for (int ni = 0; ni < 4; ++ni) {
                    float v = acc[mi][ni][r];
                    v = (v != v) ? 0.f : v;   // NaN guard per reference
                    h[(size_t)grow * HD + wn0 + ni * 16 + l15] = __float2bfloat16(v);
                }
            }
        }
    }
    if (wave == 0) {
        #pragma unroll
        for (int mi = 0; mi < 4; ++mi) {
            #pragma unroll
            for (int r = 0; r < 4; ++r) {
                int grow = row0 + mi * 16 + kg * 4 + r;
                if (grow < N_NODES) {
                    float v = accLR[mi][r];
                    if (l15 < 8) hl[grow * 8 + l15] = v;
                    else         hr[grow * 8 + (l15 - 8)] = v;
                }
            }
        }
    }
}

// ---- scans ----
__global__ void scan1(const int* __restrict__ deg, int* __restrict__ excl,
                      int* __restrict__ bsums, int n) {
    __shared__ int sm[256];
    int tid = threadIdx.x;
    int i = blockIdx.x * 256 + tid;
    int v = (i < n) ? deg[i] : 0;
    sm[tid] = v;
    __syncthreads();
    int acc = v;
    for (int off = 1; off < 256; off <<= 1) {
        int add = (tid >= off) ? sm[tid - off] : 0;
        __syncthreads();
        acc += add;
        sm[tid] = acc;
        __syncthreads();
    }
    if (i < n) excl[i] = acc - v;
    if (tid == 255) bsums[blockIdx.x] = acc;
}

__global__ void scan2(int* __restrict__ bsums, int nb) {
    __shared__ int sm[256];
    int tid = threadIdx.x;
    int v = (tid < nb) ? bsums[tid] : 0;
    sm[tid] = v;
    __syncthreads();
    int acc = v;
    for (int off = 1; off < 256; off <<= 1) {
        int add = (tid >= off) ? sm[tid - off] : 0;
        __syncthreads();
        acc += add;
        sm[tid] = acc;
        __syncthreads();
    }
    if (tid < nb) bsums[tid] = acc - v;   // exclusive
}

__global__ void scan3(int* __restrict__ offs, const int* __restrict__ bsums,
                      int n, int total) {
    int i = blockIdx.x * 256 + threadIdx.x;
    if (i < n) offs[i] += bsums[blockIdx.x];
    if (i == 0) offs[n] = total;
}

__global__ void scatter_edges(const int* __restrict__ col,
                              const int* __restrict__ row,
                              const int* __restrict__ tp,
                              const int* __restrict__ offs,
                              const int* __restrict__ pos,
                              int2* __restrict__ epack) {
    int e = blockIdx.x * 256 + threadIdx.x;
    if (e < N_EDGES) {
        int c = col[e];
        epack[offs[c] + pos[e]] = make_int2(row[e] | (tp[e] << 17), e);
    }
}

// ---- fused per-node softmax + aggregation: one wave/node, no atomics ----
// pass A: online (m,z) per head, cache s/rt/eid in LDS
// pass A5: finalize a = exp(s-m)*zinv once per (edge,head); write att
// pass B: pure gather-accumulate from LDS-cached (r, a)
__global__ __launch_bounds__(256) void node_fused(const int* __restrict__ offs,
                                                  const int2* __restrict__ epack,
                                                  const float* __restrict__ hl,
                                                  const float* __restrict__ hr,
                                                  const float* __restrict__ he,
                                                  const __hip_bfloat16* __restrict__ h,
                                                  float* __restrict__ out,
                                                  float* __restrict__ att) {
    __shared__ float sc[4][CAP][8];
    __shared__ int   srt[4][CAP];
    __shared__ int   sei[4][CAP];
    int wid = threadIdx.x >> 6;
    int lane = threadIdx.x & 63;
    int n = blockIdx.x * 4 + wid;
    if (n >= N_NODES) return;
    int beg = offs[n], end = offs[n + 1], deg = end - beg;
    int cdeg = deg < CAP ? deg : CAP;

    // pass A: lanes = 8 slots x 8 heads
    int slot = lane >> 3, hh = lane & 7;
    float hrv = hr[n * 8 + hh];
    float m = -1e30f, z = 0.f;
    for (int jj = slot; jj < deg; jj += 8) {
        int2 p = epack[beg + jj];
        int r = p.x & 0x1FFFF, t = p.x >> 17;
        if (jj < CAP && hh == 0) { srt[wid][jj] = p.x; sei[wid][jj] = p.y; }
        float s = hl[r * 8 + hh] + hrv + he[t * 8 + hh];
        s = s > 0.f ? s : NEG_SLOPE * s;
        if (jj < CAP) sc[wid][jj][hh] = s;
        if (s > m) { z = z * __expf(m - s) + 1.f; m = s; }
        else       { z += __expf(s - m); }
    }
    {   // merge 8 slots (fixed head)
        float mo, zo, M;
        mo = __shfl_xor(m, 8);  zo = __shfl_xor(z, 8);
        M = fmaxf(m, mo); z = z * __expf(m - M) + zo * __expf(mo - M); m = M;
        mo = __shfl_xor(m, 16); zo = __shfl_xor(z, 16);
        M = fmaxf(m, mo); z = z * __expf(m - M) + zo * __expf(mo - M); m = M;
        mo = __shfl_xor(m, 32); zo = __shfl_xor(z, 32);
        M = fmaxf(m, mo); z = z * __expf(m - M) + zo * __expf(mo - M); m = M;
    }
    float zinv = 1.0f / z;

    // pass A5: finalize a once per (edge,head); att write 32B-coalesced
    for (int jj = slot; jj < cdeg; jj += 8) {
        float a = __expf(sc[wid][jj][hh] - m) * zinv;
        sc[wid][jj][hh] = a;
        att[(size_t)sei[wid][jj] * 8 + hh] = a;
    }

    // pass B: lane = head(lane>>3) x 4-col group; 4x unrolled gather-acc
    int hh3 = lane >> 3;
    float4 acc = make_float4(0.f, 0.f, 0.f, 0.f);
    int jj = 0;
    for (; jj + 4 <= cdeg; jj += 4) {
        int r0 = srt[wid][jj]     & 0x1FFFF;
        int r1 = srt[wid][jj + 1] & 0x1FFFF;
        int r2 = srt[wid][jj + 2] & 0x1FFFF;
        int r3 = srt[wid][jj + 3] & 0x1FFFF;
        short4_t hv0 = *(const short4_t*)&h[(size_t)r0 * HD + lane * 4];
        short4_t hv1 = *(const short4_t*)&h[(size_t)r1 * HD + lane * 4];
        short4_t hv2 = *(const short4_t*)&h[(size_t)r2 * HD + lane * 4];
        short4_t hv3 = *(const short4_t*)&h[(size_t)r3 * HD + lane * 4];
        float a0 = sc[wid][jj][hh3],     a1 = sc[wid][jj + 1][hh3];
        float a2 = sc[wid][jj + 2][hh3], a3 = sc[wid][jj + 3][hh3];
        acc.x += a0 * b2f(hv0[0]) + a1 * b2f(hv1[0]) + a2 * b2f(hv2[0]) + a3 * b2f(hv3[0]);
        acc.y += a0 * b2f(hv0[1]) + a1 * b2f(hv1[1]) + a2 * b2f(hv2[1]) + a3 * b2f(hv3[1]);
        acc.z += a0 * b2f(hv0[2]) + a1 * b2f(hv1[2]) + a2 * b2f(hv2[2]) + a3 * b2f(hv3[2]);
        acc.w += a0 * b2f(hv0[3]) + a1 * b2f(hv1[3]) + a2 * b2f(hv2[3]) + a3 * b2f(hv3[3]);
    }
    for (; jj < cdeg; ++jj) {
        int r = srt[wid][jj] & 0x1FFFF;
        float a = sc[wid][jj][hh3];
        short4_t hv = *(const short4_t*)&h[(size_t)r * HD + lane * 4];
        acc.x += a * b2f(hv[0]);
        acc.y += a * b2f(hv[1]);
        acc.z += a * b2f(hv[2]);
        acc.w += a * b2f(hv[3]);
    }
    // overflow path (deg > CAP): recompute with merged stats
    if (deg > CAP) {
        int dg = lane & 7;
        float m3 = __shfl(m, hh3);
        float zinv3 = __shfl(zinv, hh3);
        float hrv3 = __shfl(hrv, hh3);
        for (jj = CAP; jj < deg; ++jj) {
            int2 p = epack[beg + jj];
            int r = p.x & 0x1FFFF, t = p.x >> 17;
            float s = hl[r * 8 + hh3] + hrv3 + he[t * 8 + hh3];
            s = s > 0.f ? s : NEG_SLOPE * s;
            float a = __expf(s - m3) * zinv3;
            if (dg == 0) att[(size_t)p.y * 8 + hh3] = a;
            short4_t hv = *(const short4_t*)&h[(size_t)r * HD + lane * 4];
            acc.x += a * b2f(hv[0]);
            acc.y += a * b2f(hv[1]);
            acc.z += a * b2f(hv[2]);
            acc.w += a * b2f(hv[3]);
        }
    }
    *(float4*)&out[(size_t)n * HD + lane * 4] = acc;
}

extern "C" void kernel_launch(void* const* d_in, const int* in_sizes, int n_in,
                              void* d_out, int out_size, void* d_ws, size_t ws_size,
                              hipStream_t stream) {
    const float* x        = (const float*)d_in[0];
    const float* W        = (const float*)d_in[1];
    const float* W_e      = (const float*)d_in[2];
    const float* edge_emb = (const float*)d_in[3];
    const float* a_l      = (const float*)d_in[4];
    const float* a_r      = (const float*)d_in[5];
    const float* a_e      = (const float*)d_in[6];
    const int*   row      = (const int*)d_in[7];
    const int*   col      = (const int*)d_in[8];
    const int*   tp       = (const int*)d_in[9];

    float* out = (float*)d_out;                       // [N, 256] f32
    float* att = out + (size_t)N_NODES * HD;          // [E, 8]   f32

    // workspace layout (4-byte words)
    __hip_bfloat16* h   = (__hip_bfloat16*)d_ws;      // 12,800,000 bf16 -> 6,400,000 w
    float* hl           = (float*)(h + 12800000);     //    400,000
    float* hr           = hl + 400000;                //    400,000
    float* he           = hr + 400000;                //         64
    __hip_bfloat16* Wt  = (__hip_bfloat16*)(he + 64); //  65,536 bf16 -> 32,768 w
    __hip_bfloat16* Wlr = Wt + 65536;                 //   4,096 bf16 ->  2,048 w
    int*   deg          = (int*)(Wlr + 4096);         //     50,000  [zeroed]
    int*   offs         = deg + 50000;                //     50,001
    int*   bsums        = offs + 50001;               //        256
    int*   pos          = bsums + 256;                //    800,000
    int*   pad          = pos + 800000;               //          1 (align epack to 8B)
    int2*  epack        = (int2*)((((uintptr_t)pad) + 7) & ~(uintptr_t)7);  // 800,000 int2

    hipMemsetAsync(deg, 0, (size_t)50000 * 4, stream);

    const int EB = (N_EDGES + 255) / 256;   // 3125
    prep<<<273 + EB, 256, 0, stream>>>(W, a_l, a_r, edge_emb, W_e, a_e, col,
                                       Wt, Wlr, he, deg, pos);

    gemm_h_mfma<<<(N_NODES + 63) / 64, 256, 0, stream>>>(x, Wt, Wlr, h, hl, hr);

    const int NB = (N_NODES + 255) / 256;   // 196
    scan1<<<NB, 256, 0, stream>>>(deg, offs, bsums, N_NODES);
    scan2<<<1, 256, 0, stream>>>(bsums, NB);
    scan3<<<NB, 256, 0, stream>>>(offs, bsums, N_NODES, N_EDGES);
    scatter_edges<<<EB, 256, 0, stream>>>(col, row, tp, offs, pos, epack);

    node_fused<<<(N_NODES + 3) / 4, 256, 0, stream>>>(offs, epack, hl, hr, he, h, out, att);
}